// Round 1
// baseline (169.228 us; speedup 1.0000x reference)
//
#include <hip/hip_runtime.h>
#include <hip/hip_fp16.h>

#define NBLK 256
#define NT   1024
#define FPAD 16   // 64 B per flag slot

typedef _Float16 h2_t __attribute__((ext_vector_type(2)));

#define AG_LD(p)    __hip_atomic_load((p), __ATOMIC_RELAXED, __HIP_MEMORY_SCOPE_AGENT)
#define AG_ST(p, v) __hip_atomic_store((p), (v), __ATOMIC_RELAXED, __HIP_MEMORY_SCOPE_AGENT)

// pack two fp32 -> fp16 pair (RNE)
__device__ __forceinline__ unsigned pkh(float a, float b) {
    const __half2 h = __floats2half2_rn(a, b);
    return __builtin_bit_cast(unsigned, h);
}
// fp16-pair dot product with fp32 accumulate (v_dot2_f32_f16)
__device__ __forceinline__ float fdot2(unsigned w, unsigned a, float c) {
#if __has_builtin(__builtin_amdgcn_fdot2)
    return __builtin_amdgcn_fdot2(__builtin_bit_cast(h2_t, w),
                                  __builtin_bit_cast(h2_t, a), c, false);
#else
    const float2 fw = __half22float2(__builtin_bit_cast(__half2, w));
    const float2 fa = __half22float2(__builtin_bit_cast(__half2, a));
    return c + fw.x * fa.x + fw.y * fa.y;
#endif
}

// Global fan-out barrier (validated R5-R10 prev session; per-batch variant regressed).
// fence=true only after P0 (publish packed weights, kill stale poison).
__device__ __forceinline__ void gridbar(int n, unsigned* flags, unsigned* rel,
                                        int bid, bool fence) {
    __syncthreads();
    if (threadIdx.x == 0)
        __hip_atomic_store(&flags[bid * FPAD], (unsigned)n, __ATOMIC_RELEASE,
                           __HIP_MEMORY_SCOPE_AGENT);
    if (bid == 0) {
        if (threadIdx.x < NBLK) {
            while ((int)__hip_atomic_load(&flags[threadIdx.x * FPAD],
                                          __ATOMIC_RELAXED,
                                          __HIP_MEMORY_SCOPE_AGENT) < n)
                __builtin_amdgcn_s_sleep(1);
        }
        __syncthreads();
        if (threadIdx.x < 16)
            __hip_atomic_store(&rel[(n * 16 + threadIdx.x) * FPAD], (unsigned)n,
                               __ATOMIC_RELEASE, __HIP_MEMORY_SCOPE_AGENT);
    } else {
        if (threadIdx.x == 0) {
            while ((int)__hip_atomic_load(&rel[(n * 16 + (bid & 15)) * FPAD],
                                          __ATOMIC_RELAXED,
                                          __HIP_MEMORY_SCOPE_AGENT) < n)
                __builtin_amdgcn_s_sleep(1);
        }
    }
    if (fence) __builtin_amdgcn_fence(__ATOMIC_ACQUIRE, "agent");
    __syncthreads();
}

// Packed fp16 weight layout: octet g = k>>3; uint at WtH[m*32768 + g*1024 +
// c*4 + ((k>>1)&3)] holds k-pair (2k, 2k+1). Lane c loads uint4 = 8 k-values.

// Per-batch softmax combine + sigmoid + U2 matvec (fp16, 4-way k-split) + updB.
// Scratch: S = 2048 floats (M plane [0,1024), den plane [1024,2048));
//          numpl = 1024 floats (num plane).
__device__ __forceinline__ float phaseB(int i, int b, int c, int rq, int tid,
                                        const float* __restrict__ part,
                                        const unsigned* __restrict__ WtH,
                                        const float* __restrict__ updB,
                                        float* S, float* numpl,
                                        float* aggl32, unsigned* aggh) {
    float M = -1e30f, den = 0.f, num = 0.f;
    const int par = i & 1;
    #pragma unroll
    for (int j = rq * 4; j < rq * 4 + 4; ++j) {
        const float* pp = part + (size_t)(par * 256 + b * 16 + j) * 768;
        const float mj = AG_LD(pp + c);
        const float dj = AG_LD(pp + 256 + c);
        const float nj = AG_LD(pp + 512 + c);
        const float Mn = fmaxf(M, mj);
        const float s = __expf(M - Mn), e = __expf(mj - Mn);
        den = den * s + dj * e;
        num = num * s + nj * e;
        M = Mn;
    }
    S[rq * 256 + c] = M;
    S[1024 + rq * 256 + c] = den;
    numpl[rq * 256 + c] = num;
    __syncthreads();
    if (rq == 0) {
        const float m0 = S[c], m1 = S[256 + c], m2 = S[512 + c], m3 = S[768 + c];
        const float Mx = fmaxf(fmaxf(m0, m1), fmaxf(m2, m3));
        const float s0 = __expf(m0 - Mx), s1 = __expf(m1 - Mx);
        const float s2 = __expf(m2 - Mx), s3 = __expf(m3 - Mx);
        const float dd = S[1024 + c] * s0 + S[1280 + c] * s1
                       + S[1536 + c] * s2 + S[1792 + c] * s3;
        const float nn = numpl[c] * s0 + numpl[256 + c] * s1
                       + numpl[512 + c] * s2 + numpl[768 + c] * s3;
        aggl32[c] = 1.f / (1.f + __expf(-(nn / dd)));
    }
    __syncthreads();
    if (tid < 128) aggh[tid] = pkh(aggl32[2 * tid], aggl32[2 * tid + 1]);
    __syncthreads();
    const unsigned* Uq = WtH + (size_t)(9 + i) * 32768;
    const int g0 = rq * 8;
    uint4 buf[8];
    #pragma unroll
    for (int j = 0; j < 8; ++j)
        buf[j] = *(const uint4*)(Uq + (size_t)(g0 + j) * 1024 + c * 4);
    float au = 0.f;
    #pragma unroll
    for (int j = 0; j < 8; ++j) {
        const uint4 w = buf[j];
        const uint4 a = *(const uint4*)&aggh[(g0 + j) * 4];
        au = fdot2(w.x, a.x, au);
        au = fdot2(w.y, a.y, au);
        au = fdot2(w.z, a.z, au);
        au = fdot2(w.w, a.w, au);
    }
    __syncthreads();
    S[rq * 256 + c] = au;
    __syncthreads();
    return S[c] + S[256 + c] + S[512 + c] + S[768 + c] + updB[i * 256 + c];
}

__global__ __launch_bounds__(NT, 4) void fused_k(
    const float* __restrict__ feat,   // [16][128][256]
    const float* __restrict__ mask,   // [16][128]
    const float* __restrict__ aggW,   // [3][256][256]
    const float* __restrict__ aggB,   // [3][256]
    const float* __restrict__ attnW,  // [3][256][512]
    const float* __restrict__ updW,   // [3][256][512]
    const float* __restrict__ updB,   // [3][256]
    unsigned* __restrict__ WtH,       // 12 * 32768 uints (fp16-pair packed)
    float* __restrict__ part,         // 2 * 256 * 768
    unsigned* flags, unsigned* rel,
    float* __restrict__ out)
{
    __shared__ __align__(16) float ldsf[12680];
    unsigned* hidh   = (unsigned*)ldsf;            // [0,1024)    8 rows x 128 pairs
    unsigned* xlh    = (unsigned*)ldsf + 1024;     // [1024,2048)
    float*    xl32   = ldsf + 2048;                // [2048,4096) 8 x 256 fp32
    float*    S      = ldsf + 4096;                // [4096,6144) combine scratch
    float*    comb   = ldsf + 6144;                // [6144,12288) 3 planes x 2048
    float*    aggl32 = ldsf + 12288;               // [12288,12544)
    unsigned* aggh   = (unsigned*)ldsf + 12544;    // [12544,12672)
    float*    msk    = ldsf + 12672;               // [12672,12680)

    const int bid = blockIdx.x;
    const int tid = threadIdx.x;
    const int c  = tid & 255;
    const int rq = tid >> 8;                  // 0..3, wave-uniform
    const int b  = bid >> 4, jj = bid & 15;
    const int row0 = b * 128 + jj * 8;

    // ---- P0a: stage hid0 = fp16(feat*mask) + mask into LDS (survives fence)
    {
        const int r = tid >> 7, pr = tid & 127;
        const float2 f = *(const float2*)(feat + (size_t)(row0 + r) * 256 + pr * 2);
        const float mv = mask[row0 + r];
        hidh[r * 128 + pr] = pkh(f.x * mv, f.y * mv);
    }
    if (tid < 8) msk[tid] = mask[row0 + tid];

    // ---- P0b: transpose + fp16-pack 12 weight mats (blocks 0..191)
    if (bid < 192) {
        float (*Tl)[65] = (float (*)[65])(ldsf + 2048);   // overlay, dead regions
        const int m = bid >> 4, t = bid & 15, tr = t >> 2, tc = t & 3;
        const float* src; int stride, off;
        if (m < 3)      { src = aggW  + (size_t)m * 65536;        stride = 256; off = 0;   }
        else if (m < 6) { src = attnW + (size_t)(m - 3) * 131072; stride = 512; off = 0;   }
        else if (m < 9) { src = updW  + (size_t)(m - 6) * 131072; stride = 512; off = 0;   }
        else            { src = updW  + (size_t)(m - 9) * 131072; stride = 512; off = 256; }
        unsigned* dstu = WtH + (size_t)m * 32768;
        {
            const int row = tid >> 4, q = (tid & 15) * 4;
            const float4 v = *(const float4*)(src + (size_t)(tr * 64 + row) * stride + off + tc * 64 + q);
            Tl[row][q + 0] = v.x; Tl[row][q + 1] = v.y;
            Tl[row][q + 2] = v.z; Tl[row][q + 3] = v.w;
        }
        __syncthreads();
        #pragma unroll
        for (int it = 0; it < 2; ++it) {
            const int j = it * 1024 + tid, cl = j >> 5, pr = j & 31;
            const unsigned val = pkh(Tl[cl][pr * 2], Tl[cl][pr * 2 + 1]);
            const int P = tc * 32 + pr, g = P >> 2, jq = P & 3;
            dstu[(size_t)g * 1024 + (tr * 64 + cl) * 4 + jq] = val;
        }
    }
    gridbar(1, flags, rel, bid, true);   // only fenced barrier

    float xu[8];
    #pragma unroll
    for (int r = 0; r < 8; ++r) xu[r] = 0.f;
    float accU = 0.f;

    for (int i = 0; i < 3; ++i) {
        if (i > 0) {
            accU = phaseB(i - 1, b, c, rq, tid, part, WtH, updB, S, comb, aggl32, aggh);
            __syncthreads();            // protect S reuse below
            if (rq == 2) {
                #pragma unroll
                for (int r = 0; r < 8; ++r)
                    S[r * 256 + c] = (xu[r] + accU) * msk[r];
            }
            __syncthreads();
            {
                const int r = tid >> 7, pr = tid & 127;
                hidh[r * 128 + pr] = pkh(S[r * 256 + pr * 2], S[r * 256 + pr * 2 + 1]);
            }
            __syncthreads();
        }

        // ---- P1: x = hid @ aggW^T + aggB. fp16 streams, 4-way k-split.
        {
            const unsigned* Wq = WtH + (size_t)i * 32768;
            const int g0 = rq * 8;
            uint4 buf[8];
            #pragma unroll
            for (int j = 0; j < 8; ++j)
                buf[j] = *(const uint4*)(Wq + (size_t)(g0 + j) * 1024 + c * 4);
            float acc[8] = {};
            #pragma unroll
            for (int j = 0; j < 8; ++j) {
                const uint4 w = buf[j];
                const int g = g0 + j;
                #pragma unroll
                for (int r = 0; r < 8; ++r) {
                    const uint4 h = *(const uint4*)&hidh[r * 128 + g * 4];
                    acc[r] = fdot2(w.x, h.x, acc[r]);
                    acc[r] = fdot2(w.y, h.y, acc[r]);
                    acc[r] = fdot2(w.z, h.z, acc[r]);
                    acc[r] = fdot2(w.w, h.w, acc[r]);
                }
            }
            if (rq != 0) {
                float* cp = comb + (size_t)(rq - 1) * 2048;
                #pragma unroll
                for (int r = 0; r < 8; ++r) cp[r * 256 + c] = acc[r];
            }
            __syncthreads();
            if (rq == 0) {
                const float bb = aggB[i * 256 + c];
                #pragma unroll
                for (int r = 0; r < 8; ++r)
                    xl32[r * 256 + c] = acc[r] + comb[r * 256 + c]
                                      + comb[2048 + r * 256 + c]
                                      + comb[4096 + r * 256 + c] + bb;
            }
            __syncthreads();
            {
                const int r = tid >> 7, pr = tid & 127;
                xlh[r * 128 + pr] = pkh(xl32[r * 256 + pr * 2], xl32[r * 256 + pr * 2 + 1]);
            }
            __syncthreads();
        }

        // ---- P2: rq0/1 stream W1 -> p ; rq2/3 stream U1 -> xU1 (fp16, k-split 2-way each)
        float pr8[8];
        {
            const unsigned* Sq = WtH + (size_t)(((rq >> 1) ? 6 : 3) + i) * 32768;
            const int g0 = (rq & 1) * 16;
            uint4 buf[8];
            #pragma unroll
            for (int j = 0; j < 8; ++j)
                buf[j] = *(const uint4*)(Sq + (size_t)(g0 + j) * 1024 + c * 4);
            float acc[8] = {};
            #pragma unroll
            for (int ph = 0; ph < 2; ++ph) {
                #pragma unroll
                for (int j = 0; j < 8; ++j) {
                    const uint4 w = buf[j];
                    if (ph < 1)
                        buf[j] = *(const uint4*)(Sq + (size_t)(g0 + 8 + j) * 1024 + c * 4);
                    const int g = g0 + ph * 8 + j;
                    #pragma unroll
                    for (int r = 0; r < 8; ++r) {
                        const uint4 h = *(const uint4*)&xlh[r * 128 + g * 4];
                        acc[r] = fdot2(w.x, h.x, acc[r]);
                        acc[r] = fdot2(w.y, h.y, acc[r]);
                        acc[r] = fdot2(w.z, h.z, acc[r]);
                        acc[r] = fdot2(w.w, h.w, acc[r]);
                    }
                }
            }
            #pragma unroll
            for (int r = 0; r < 8; ++r) pr8[r] = acc[r];
        }
        // pair combines: rq1 -> comb plane0 (W1), rq3 -> comb plane1 (U1)
        if (rq == 1 || rq == 3) {
            float* cp = comb + (size_t)(rq >> 1) * 2048;
            #pragma unroll
            for (int r = 0; r < 8; ++r) cp[r * 256 + c] = pr8[r];
        }
        __syncthreads();
        if (rq == 0) {
            float p8[8];
            #pragma unroll
            for (int r = 0; r < 8; ++r) p8[r] = pr8[r] + comb[r * 256 + c];
            float m8 = p8[0];
            #pragma unroll
            for (int r = 1; r < 8; ++r) m8 = fmaxf(m8, p8[r]);
            float d8 = 0.f, n8 = 0.f;
            #pragma unroll
            for (int r = 0; r < 8; ++r) {
                const float e = __expf(p8[r] - m8);
                d8 += e;
                n8 += e * xl32[r * 256 + c];
            }
            float* pb = part + (size_t)((i & 1) * 256 + bid) * 768;
            AG_ST(pb + c, m8);
            AG_ST(pb + 256 + c, d8);
            AG_ST(pb + 512 + c, n8);
        } else if (rq == 2) {
            #pragma unroll
            for (int r = 0; r < 8; ++r) xu[r] = pr8[r] + comb[2048 + r * 256 + c];
        }
        gridbar(i + 2, flags, rel, bid, false);   // no fence: L2 stays warm
    }

    // ---- final combine + epilogue: out = xU1 + accU (fp32 path)
    accU = phaseB(2, b, c, rq, tid, part, WtH, updB, S, comb, aggl32, aggh);
    if (rq == 2) {
        #pragma unroll
        for (int r = 0; r < 8; ++r)
            out[(size_t)(row0 + r) * 256 + c] = xu[r] + accU;
    }
}

extern "C" void kernel_launch(void* const* d_in, const int* in_sizes, int n_in,
                              void* d_out, int out_size, void* d_ws, size_t ws_size,
                              hipStream_t stream) {
    const float* feat  = (const float*)d_in[0];
    const float* mask  = (const float*)d_in[1];
    const float* aggW  = (const float*)d_in[2];
    const float* aggB  = (const float*)d_in[3];
    const float* attnW = (const float*)d_in[4];
    // d_in[5] = attnB: cancels in softmax (constant along the s axis)
    const float* updW  = (const float*)d_in[6];
    const float* updB  = (const float*)d_in[7];

    unsigned* WtH = (unsigned*)d_ws;                   // 12 * 32768 uints
    float* part = (float*)(WtH + 12 * 32768);          // 2 * 256 * 768 floats
    unsigned* flags = (unsigned*)(part + 2 * 256 * 768);
    unsigned* rel   = flags + NBLK * FPAD;             // barriers * 16 lines

    fused_k<<<NBLK, NT, 0, stream>>>(
        feat, mask, aggW, aggB, attnW, updW, updB,
        WtH, part, flags, rel, (float*)d_out);
}

// Round 2
// 164.767 us; speedup vs baseline: 1.0271x; 1.0271x over previous
//
#include <hip/hip_runtime.h>
#include <hip/hip_fp16.h>

#define NBLK 256
#define NT   1024
#define FPAD 16   // 64 B per flag slot

typedef _Float16 h2_t __attribute__((ext_vector_type(2)));

#define AG_LD(p)    __hip_atomic_load((p), __ATOMIC_RELAXED, __HIP_MEMORY_SCOPE_AGENT)
#define AG_ST(p, v) __hip_atomic_store((p), (v), __ATOMIC_RELAXED, __HIP_MEMORY_SCOPE_AGENT)

// pack two fp32 -> fp16 pair (RNE)
__device__ __forceinline__ unsigned pkh(float a, float b) {
    const __half2 h = __floats2half2_rn(a, b);
    return __builtin_bit_cast(unsigned, h);
}
// fp16-pair dot product with fp32 accumulate (v_dot2_f32_f16)
__device__ __forceinline__ float fdot2(unsigned w, unsigned a, float c) {
#if __has_builtin(__builtin_amdgcn_fdot2)
    return __builtin_amdgcn_fdot2(__builtin_bit_cast(h2_t, w),
                                  __builtin_bit_cast(h2_t, a), c, false);
#else
    const float2 fw = __half22float2(__builtin_bit_cast(__half2, w));
    const float2 fa = __half22float2(__builtin_bit_cast(__half2, a));
    return c + fw.x * fa.x + fw.y * fa.y;
#endif
}

// Global fan-out barrier (validated R5-R10 prev session; per-batch variant regressed).
// fence=true only after P0 (publish packed weights, kill stale poison).
__device__ __forceinline__ void gridbar(int n, unsigned* flags, unsigned* rel,
                                        int bid, bool fence) {
    __syncthreads();
    if (threadIdx.x == 0)
        __hip_atomic_store(&flags[bid * FPAD], (unsigned)n, __ATOMIC_RELEASE,
                           __HIP_MEMORY_SCOPE_AGENT);
    if (bid == 0) {
        if (threadIdx.x < NBLK) {
            while ((int)__hip_atomic_load(&flags[threadIdx.x * FPAD],
                                          __ATOMIC_RELAXED,
                                          __HIP_MEMORY_SCOPE_AGENT) < n)
                __builtin_amdgcn_s_sleep(1);
        }
        __syncthreads();
        if (threadIdx.x < 16)
            __hip_atomic_store(&rel[(n * 16 + threadIdx.x) * FPAD], (unsigned)n,
                               __ATOMIC_RELEASE, __HIP_MEMORY_SCOPE_AGENT);
    } else {
        if (threadIdx.x == 0) {
            while ((int)__hip_atomic_load(&rel[(n * 16 + (bid & 15)) * FPAD],
                                          __ATOMIC_RELAXED,
                                          __HIP_MEMORY_SCOPE_AGENT) < n)
                __builtin_amdgcn_s_sleep(1);
        }
    }
    if (fence) __builtin_amdgcn_fence(__ATOMIC_ACQUIRE, "agent");
    __syncthreads();
}

// Packed fp16 weight layout: octet g = k>>3; uint at WtH[m*32768 + g*1024 +
// c*4 + ((k>>1)&3)] holds k-pair (2k, 2k+1). Lane c loads uint4 = 8 k-values.

// Per-batch softmax combine + sigmoid + U2 matvec (fp16, 4-way k-split) + updB.
// Scratch: S = 2048 floats (M plane [0,1024), den plane [1024,2048));
//          numpl = 1024 floats (num plane).
__device__ __forceinline__ float phaseB(int i, int b, int c, int rq, int tid,
                                        const float* __restrict__ part,
                                        const unsigned* __restrict__ WtH,
                                        const float* __restrict__ updB,
                                        float* S, float* numpl,
                                        float* aggl32, unsigned* aggh) {
    float M = -1e30f, den = 0.f, num = 0.f;
    const int par = i & 1;
    #pragma unroll
    for (int j = rq * 4; j < rq * 4 + 4; ++j) {
        const float* pp = part + (size_t)(par * 256 + b * 16 + j) * 768;
        const float mj = AG_LD(pp + c);
        const float dj = AG_LD(pp + 256 + c);
        const float nj = AG_LD(pp + 512 + c);
        const float Mn = fmaxf(M, mj);
        const float s = __expf(M - Mn), e = __expf(mj - Mn);
        den = den * s + dj * e;
        num = num * s + nj * e;
        M = Mn;
    }
    S[rq * 256 + c] = M;
    S[1024 + rq * 256 + c] = den;
    numpl[rq * 256 + c] = num;
    __syncthreads();
    if (rq == 0) {
        const float m0 = S[c], m1 = S[256 + c], m2 = S[512 + c], m3 = S[768 + c];
        const float Mx = fmaxf(fmaxf(m0, m1), fmaxf(m2, m3));
        const float s0 = __expf(m0 - Mx), s1 = __expf(m1 - Mx);
        const float s2 = __expf(m2 - Mx), s3 = __expf(m3 - Mx);
        const float dd = S[1024 + c] * s0 + S[1280 + c] * s1
                       + S[1536 + c] * s2 + S[1792 + c] * s3;
        const float nn = numpl[c] * s0 + numpl[256 + c] * s1
                       + numpl[512 + c] * s2 + numpl[768 + c] * s3;
        aggl32[c] = 1.f / (1.f + __expf(-(nn / dd)));
    }
    __syncthreads();
    if (tid < 128) aggh[tid] = pkh(aggl32[2 * tid], aggl32[2 * tid + 1]);
    __syncthreads();
    const unsigned* Uq = WtH + (size_t)(9 + i) * 32768;
    const int g0 = rq * 8;
    uint4 buf[8];
    #pragma unroll
    for (int j = 0; j < 8; ++j)
        buf[j] = *(const uint4*)(Uq + (size_t)(g0 + j) * 1024 + c * 4);
    float au = 0.f;
    #pragma unroll
    for (int j = 0; j < 8; ++j) {
        const uint4 w = buf[j];
        const uint4 a = *(const uint4*)&aggh[(g0 + j) * 4];
        au = fdot2(w.x, a.x, au);
        au = fdot2(w.y, a.y, au);
        au = fdot2(w.z, a.z, au);
        au = fdot2(w.w, a.w, au);
    }
    __syncthreads();
    S[rq * 256 + c] = au;
    __syncthreads();
    return S[c] + S[256 + c] + S[512 + c] + S[768 + c] + updB[i * 256 + c];
}

__global__ __launch_bounds__(NT)
__attribute__((amdgpu_waves_per_eu(4, 4)))   // pin EXACTLY 1 block/CU: 128-VGPR budget, no spill-squeeze
void fused_k(
    const float* __restrict__ feat,   // [16][128][256]
    const float* __restrict__ mask,   // [16][128]
    const float* __restrict__ aggW,   // [3][256][256]
    const float* __restrict__ aggB,   // [3][256]
    const float* __restrict__ attnW,  // [3][256][512]
    const float* __restrict__ updW,   // [3][256][512]
    const float* __restrict__ updB,   // [3][256]
    unsigned* __restrict__ WtH,       // 12 * 32768 uints (fp16-pair packed)
    float* __restrict__ part,         // 2 * 256 * 768
    unsigned* flags, unsigned* rel,
    float* __restrict__ out)
{
    __shared__ __align__(16) float ldsf[12680];
    unsigned* hidh   = (unsigned*)ldsf;            // [0,1024)    8 rows x 128 pairs
    unsigned* xlh    = (unsigned*)ldsf + 1024;     // [1024,2048)
    float*    xl32   = ldsf + 2048;                // [2048,4096) 8 x 256 fp32
    float*    S      = ldsf + 4096;                // [4096,6144) combine scratch
    float*    comb   = ldsf + 6144;                // [6144,12288) 3 planes x 2048
    float*    aggl32 = ldsf + 12288;               // [12288,12544)
    unsigned* aggh   = (unsigned*)ldsf + 12544;    // [12544,12672)
    float*    msk    = ldsf + 12672;               // [12672,12680)

    const int bid = blockIdx.x;
    const int tid = threadIdx.x;
    const int c  = tid & 255;
    const int rq = tid >> 8;                  // 0..3, wave-uniform
    const int b  = bid >> 4, jj = bid & 15;
    const int row0 = b * 128 + jj * 8;

    // ---- P0a: stage hid0 = fp16(feat*mask) + mask into LDS (survives fence)
    {
        const int r = tid >> 7, pr = tid & 127;
        const float2 f = *(const float2*)(feat + (size_t)(row0 + r) * 256 + pr * 2);
        const float mv = mask[row0 + r];
        hidh[r * 128 + pr] = pkh(f.x * mv, f.y * mv);
    }
    if (tid < 8) msk[tid] = mask[row0 + tid];

    // ---- P0b: transpose + fp16-pack 12 weight mats (blocks 0..191)
    if (bid < 192) {
        float (*Tl)[65] = (float (*)[65])(ldsf + 2048);   // overlay, dead regions
        const int m = bid >> 4, t = bid & 15, tr = t >> 2, tc = t & 3;
        const float* src; int stride, off;
        if (m < 3)      { src = aggW  + (size_t)m * 65536;        stride = 256; off = 0;   }
        else if (m < 6) { src = attnW + (size_t)(m - 3) * 131072; stride = 512; off = 0;   }
        else if (m < 9) { src = updW  + (size_t)(m - 6) * 131072; stride = 512; off = 0;   }
        else            { src = updW  + (size_t)(m - 9) * 131072; stride = 512; off = 256; }
        unsigned* dstu = WtH + (size_t)m * 32768;
        {
            const int row = tid >> 4, q = (tid & 15) * 4;
            const float4 v = *(const float4*)(src + (size_t)(tr * 64 + row) * stride + off + tc * 64 + q);
            Tl[row][q + 0] = v.x; Tl[row][q + 1] = v.y;
            Tl[row][q + 2] = v.z; Tl[row][q + 3] = v.w;
        }
        __syncthreads();
        #pragma unroll
        for (int it = 0; it < 2; ++it) {
            const int j = it * 1024 + tid, cl = j >> 5, pr = j & 31;
            const unsigned val = pkh(Tl[cl][pr * 2], Tl[cl][pr * 2 + 1]);
            const int P = tc * 32 + pr, g = P >> 2, jq = P & 3;
            dstu[(size_t)g * 1024 + (tr * 64 + cl) * 4 + jq] = val;
        }
    }
    gridbar(1, flags, rel, bid, true);   // only fenced barrier

    float xu[8];
    #pragma unroll
    for (int r = 0; r < 8; ++r) xu[r] = 0.f;
    float accU = 0.f;

    for (int i = 0; i < 3; ++i) {
        if (i > 0) {
            accU = phaseB(i - 1, b, c, rq, tid, part, WtH, updB, S, comb, aggl32, aggh);
            __syncthreads();            // protect S reuse below
            if (rq == 2) {
                #pragma unroll
                for (int r = 0; r < 8; ++r)
                    S[r * 256 + c] = (xu[r] + accU) * msk[r];
            }
            __syncthreads();
            {
                const int r = tid >> 7, pr = tid & 127;
                hidh[r * 128 + pr] = pkh(S[r * 256 + pr * 2], S[r * 256 + pr * 2 + 1]);
            }
            __syncthreads();
        }

        // ---- P1: x = hid @ aggW^T + aggB. fp16 streams, 4-way k-split.
        {
            const unsigned* Wq = WtH + (size_t)i * 32768;
            const int g0 = rq * 8;
            uint4 buf[8];
            #pragma unroll
            for (int j = 0; j < 8; ++j)
                buf[j] = *(const uint4*)(Wq + (size_t)(g0 + j) * 1024 + c * 4);
            float acc[8] = {};
            #pragma unroll
            for (int j = 0; j < 8; ++j) {
                const uint4 w = buf[j];
                const int g = g0 + j;
                #pragma unroll
                for (int r = 0; r < 8; ++r) {
                    const uint4 h = *(const uint4*)&hidh[r * 128 + g * 4];
                    acc[r] = fdot2(w.x, h.x, acc[r]);
                    acc[r] = fdot2(w.y, h.y, acc[r]);
                    acc[r] = fdot2(w.z, h.z, acc[r]);
                    acc[r] = fdot2(w.w, h.w, acc[r]);
                }
            }
            if (rq != 0) {
                float* cp = comb + (size_t)(rq - 1) * 2048;
                #pragma unroll
                for (int r = 0; r < 8; ++r) cp[r * 256 + c] = acc[r];
            }
            __syncthreads();
            if (rq == 0) {
                const float bb = aggB[i * 256 + c];
                #pragma unroll
                for (int r = 0; r < 8; ++r)
                    xl32[r * 256 + c] = acc[r] + comb[r * 256 + c]
                                      + comb[2048 + r * 256 + c]
                                      + comb[4096 + r * 256 + c] + bb;
            }
            __syncthreads();
            {
                const int r = tid >> 7, pr = tid & 127;
                xlh[r * 128 + pr] = pkh(xl32[r * 256 + pr * 2], xl32[r * 256 + pr * 2 + 1]);
            }
            __syncthreads();
        }

        // ---- P2: rq0/1 stream W1 -> p ; rq2/3 stream U1 -> xU1 (fp16, k-split 2-way each)
        float pr8[8];
        {
            const unsigned* Sq = WtH + (size_t)(((rq >> 1) ? 6 : 3) + i) * 32768;
            const int g0 = (rq & 1) * 16;
            uint4 buf[8];
            #pragma unroll
            for (int j = 0; j < 8; ++j)
                buf[j] = *(const uint4*)(Sq + (size_t)(g0 + j) * 1024 + c * 4);
            float acc[8] = {};
            #pragma unroll
            for (int ph = 0; ph < 2; ++ph) {
                #pragma unroll
                for (int j = 0; j < 8; ++j) {
                    const uint4 w = buf[j];
                    if (ph < 1)
                        buf[j] = *(const uint4*)(Sq + (size_t)(g0 + 8 + j) * 1024 + c * 4);
                    const int g = g0 + ph * 8 + j;
                    #pragma unroll
                    for (int r = 0; r < 8; ++r) {
                        const uint4 h = *(const uint4*)&xlh[r * 128 + g * 4];
                        acc[r] = fdot2(w.x, h.x, acc[r]);
                        acc[r] = fdot2(w.y, h.y, acc[r]);
                        acc[r] = fdot2(w.z, h.z, acc[r]);
                        acc[r] = fdot2(w.w, h.w, acc[r]);
                    }
                }
            }
            #pragma unroll
            for (int r = 0; r < 8; ++r) pr8[r] = acc[r];
        }
        // pair combines: rq1 -> comb plane0 (W1), rq3 -> comb plane1 (U1)
        if (rq == 1 || rq == 3) {
            float* cp = comb + (size_t)(rq >> 1) * 2048;
            #pragma unroll
            for (int r = 0; r < 8; ++r) cp[r * 256 + c] = pr8[r];
        }
        __syncthreads();
        if (rq == 0) {
            float p8[8];
            #pragma unroll
            for (int r = 0; r < 8; ++r) p8[r] = pr8[r] + comb[r * 256 + c];
            float m8 = p8[0];
            #pragma unroll
            for (int r = 1; r < 8; ++r) m8 = fmaxf(m8, p8[r]);
            float d8 = 0.f, n8 = 0.f;
            #pragma unroll
            for (int r = 0; r < 8; ++r) {
                const float e = __expf(p8[r] - m8);
                d8 += e;
                n8 += e * xl32[r * 256 + c];
            }
            float* pb = part + (size_t)((i & 1) * 256 + bid) * 768;
            AG_ST(pb + c, m8);
            AG_ST(pb + 256 + c, d8);
            AG_ST(pb + 512 + c, n8);
        } else if (rq == 2) {
            #pragma unroll
            for (int r = 0; r < 8; ++r) xu[r] = pr8[r] + comb[2048 + r * 256 + c];
        }
        gridbar(i + 2, flags, rel, bid, false);   // no fence: L2 stays warm
    }

    // ---- final combine + epilogue: out = xU1 + accU (fp32 path)
    accU = phaseB(2, b, c, rq, tid, part, WtH, updB, S, comb, aggl32, aggh);
    if (rq == 2) {
        #pragma unroll
        for (int r = 0; r < 8; ++r)
            out[(size_t)(row0 + r) * 256 + c] = xu[r] + accU;
    }
}

extern "C" void kernel_launch(void* const* d_in, const int* in_sizes, int n_in,
                              void* d_out, int out_size, void* d_ws, size_t ws_size,
                              hipStream_t stream) {
    const float* feat  = (const float*)d_in[0];
    const float* mask  = (const float*)d_in[1];
    const float* aggW  = (const float*)d_in[2];
    const float* aggB  = (const float*)d_in[3];
    const float* attnW = (const float*)d_in[4];
    // d_in[5] = attnB: cancels in softmax (constant along the s axis)
    const float* updW  = (const float*)d_in[6];
    const float* updB  = (const float*)d_in[7];

    unsigned* WtH = (unsigned*)d_ws;                   // 12 * 32768 uints
    float* part = (float*)(WtH + 12 * 32768);          // 2 * 256 * 768 floats
    unsigned* flags = (unsigned*)(part + 2 * 256 * 768);
    unsigned* rel   = flags + NBLK * FPAD;             // barriers * 16 lines

    fused_k<<<NBLK, NT, 0, stream>>>(
        feat, mask, aggW, aggB, attnW, updW, updB,
        WtH, part, flags, rel, (float*)d_out);
}

// Round 3
// 161.344 us; speedup vs baseline: 1.0489x; 1.0212x over previous
//
#include <hip/hip_runtime.h>
#include <hip/hip_fp16.h>

#define NBLK 256
#define NT   512
#define FPAD 16   // 64 B per flag slot

typedef _Float16 h2_t __attribute__((ext_vector_type(2)));

#define AG_LD(p)    __hip_atomic_load((p), __ATOMIC_RELAXED, __HIP_MEMORY_SCOPE_AGENT)
#define AG_ST(p, v) __hip_atomic_store((p), (v), __ATOMIC_RELAXED, __HIP_MEMORY_SCOPE_AGENT)

// pack two fp32 -> fp16 pair (RNE)
__device__ __forceinline__ unsigned pkh(float a, float b) {
    const __half2 h = __floats2half2_rn(a, b);
    return __builtin_bit_cast(unsigned, h);
}
// fp16-pair dot product with fp32 accumulate (v_dot2_f32_f16)
__device__ __forceinline__ float fdot2(unsigned w, unsigned a, float c) {
#if __has_builtin(__builtin_amdgcn_fdot2)
    return __builtin_amdgcn_fdot2(__builtin_bit_cast(h2_t, w),
                                  __builtin_bit_cast(h2_t, a), c, false);
#else
    const float2 fw = __half22float2(__builtin_bit_cast(__half2, w));
    const float2 fa = __half22float2(__builtin_bit_cast(__half2, a));
    return c + fw.x * fa.x + fw.y * fa.y;
#endif
}

// ---- split-phase all-to-all barrier ----
// arrive: identical store semantics to validated gridbar fan-in.
// wait: every block runs block0's validated poll loop over all 256 flags.
__device__ __forceinline__ void bar_arrive(int n, unsigned* flags, int bid) {
    __syncthreads();
    if (threadIdx.x == 0)
        __hip_atomic_store(&flags[bid * FPAD], (unsigned)n, __ATOMIC_RELEASE,
                           __HIP_MEMORY_SCOPE_AGENT);
}
__device__ __forceinline__ void bar_wait(int n, unsigned* flags, bool fence) {
    if (threadIdx.x < NBLK) {
        while ((int)__hip_atomic_load(&flags[threadIdx.x * FPAD],
                                      __ATOMIC_RELAXED,
                                      __HIP_MEMORY_SCOPE_AGENT) < n)
            __builtin_amdgcn_s_sleep(1);
    }
    if (fence) __builtin_amdgcn_fence(__ATOMIC_ACQUIRE, "agent");
    __syncthreads();
}

// Packed fp16 weight layout: octet g = k>>3; uint at WtH[m*32768 + g*1024 +
// c*4 + ((k>>1)&3)] holds k-pair (2k, 2k+1). Lane c loads uint4 = 8 k-values.

// 16-octet (half-k) fp16 matvec stream: acc[r] += W[c, k-half] . src[r, k-half]
__device__ __forceinline__ void stream16(const unsigned* __restrict__ Wq, int g0,
                                         int c, const unsigned* __restrict__ src,
                                         float* acc) {
    uint4 buf[8];
    #pragma unroll
    for (int j = 0; j < 8; ++j)
        buf[j] = *(const uint4*)(Wq + (size_t)(g0 + j) * 1024 + c * 4);
    #pragma unroll
    for (int ph = 0; ph < 2; ++ph) {
        #pragma unroll
        for (int j = 0; j < 8; ++j) {
            const uint4 w = buf[j];
            if (ph < 1)
                buf[j] = *(const uint4*)(Wq + (size_t)(g0 + 8 + j) * 1024 + c * 4);
            const int g = g0 + ph * 8 + j;
            #pragma unroll
            for (int r = 0; r < 8; ++r) {
                const uint4 h = *(const uint4*)&src[r * 128 + g * 4];
                acc[r] = fdot2(w.x, h.x, acc[r]);
                acc[r] = fdot2(w.y, h.y, acc[r]);
                acc[r] = fdot2(w.z, h.z, acc[r]);
                acc[r] = fdot2(w.w, h.w, acc[r]);
            }
        }
    }
}

__global__ __launch_bounds__(NT, 2) void fused_k(
    const float* __restrict__ feat,   // [16][128][256]
    const float* __restrict__ mask,   // [16][128]
    const float* __restrict__ aggW,   // [3][256][256]
    const float* __restrict__ aggB,   // [3][256]
    const float* __restrict__ attnW,  // [3][256][512]
    const float* __restrict__ updW,   // [3][256][512]
    const float* __restrict__ updB,   // [3][256]
    unsigned* __restrict__ WtH,       // 12 * 32768 uints (fp16-pair packed)
    float* __restrict__ part,         // 2 * 256 * 768
    unsigned* flags, unsigned* rel,
    float* __restrict__ out)
{
    __shared__ __align__(16) float ldsf[6216];
    unsigned* hidh   = (unsigned*)ldsf;            // [0,1024)    8 rows x 128 pairs
    unsigned* xlh    = (unsigned*)ldsf + 1024;     // [1024,2048) x as fp16 pairs
    float*    msk    = ldsf + 2048;                // [2048,2056)
    float*    comb   = ldsf + 2056;                // [2056,4104) one combine plane
    float*    S      = ldsf + 4104;                // [4104,5640) 3 softmax planes
    float*    aggl32 = ldsf + 5640;                // [5640,5896)
    unsigned* aggh   = (unsigned*)ldsf + 5896;     // [5896,6024)
    (void)rel;

    const int bid = blockIdx.x;
    const int tid = threadIdx.x;
    const int c  = tid & 255;
    const int rq = tid >> 8;                  // 0..1, wave-uniform
    const int b  = bid >> 4, jj = bid & 15;
    const int row0 = b * 128 + jj * 8;

    // ---- P0a: stage hid0 = fp16(feat*mask) + mask into LDS (survives fence)
    #pragma unroll
    for (int it = 0; it < 2; ++it) {
        const int j = it * 512 + tid, r = j >> 7, pr = j & 127;
        const float2 f = *(const float2*)(feat + (size_t)(row0 + r) * 256 + pr * 2);
        const float mv = mask[row0 + r];
        hidh[r * 128 + pr] = pkh(f.x * mv, f.y * mv);
    }
    if (tid < 8) msk[tid] = mask[row0 + tid];

    // ---- P0b: transpose + fp16-pack 12 weight mats (blocks 0..191)
    if (bid < 192) {
        float (*Tl)[65] = (float (*)[65])(ldsf + 2056);   // overlay, dead regions
        const int m = bid >> 4, t = bid & 15, tr = t >> 2, tc = t & 3;
        const float* src; int stride, off;
        if (m < 3)      { src = aggW  + (size_t)m * 65536;        stride = 256; off = 0;   }
        else if (m < 6) { src = attnW + (size_t)(m - 3) * 131072; stride = 512; off = 0;   }
        else if (m < 9) { src = updW  + (size_t)(m - 6) * 131072; stride = 512; off = 0;   }
        else            { src = updW  + (size_t)(m - 9) * 131072; stride = 512; off = 256; }
        unsigned* dstu = WtH + (size_t)m * 32768;
        #pragma unroll
        for (int it = 0; it < 2; ++it) {
            const int j = it * 512 + tid, row = j >> 4, q = (j & 15) * 4;
            const float4 v = *(const float4*)(src + (size_t)(tr * 64 + row) * stride + off + tc * 64 + q);
            Tl[row][q + 0] = v.x; Tl[row][q + 1] = v.y;
            Tl[row][q + 2] = v.z; Tl[row][q + 3] = v.w;
        }
        __syncthreads();
        #pragma unroll
        for (int it = 0; it < 4; ++it) {
            const int j = it * 512 + tid, cl = j >> 5, pr = j & 31;
            const unsigned val = pkh(Tl[cl][pr * 2], Tl[cl][pr * 2 + 1]);
            const int P = tc * 32 + pr, g = P >> 2, jq = P & 3;
            dstu[(size_t)g * 1024 + (tr * 64 + cl) * 4 + jq] = val;
        }
    }
    bar_arrive(1, flags, bid);
    bar_wait(1, flags, true);            // only fenced barrier (weights published)

    const int g0 = rq * 16;              // half-k octet base for this rq group

    for (int i = 0; i < 3; ++i) {
        float x32[8];                    // rq0: x row values (regs, no LDS plane)
        float xu[8];                     // rq1: U1 partial

        // ---- P1: x = hid @ aggW^T + aggB (k-split 2-way)
        {
            float acc[8] = {};
            stream16(WtH + (size_t)i * 32768, g0, c, hidh, acc);
            if (rq == 1) {
                #pragma unroll
                for (int r = 0; r < 8; ++r) comb[r * 256 + c] = acc[r];
            }
            __syncthreads();
            if (rq == 0) {
                const float bb = aggB[i * 256 + c];
                #pragma unroll
                for (int r = 0; r < 8; ++r) {
                    x32[r] = acc[r] + comb[r * 256 + c] + bb;
                    const float xo = __shfl_xor(x32[r], 1);
                    if (!(c & 1)) xlh[r * 128 + (c >> 1)] = pkh(x32[r], xo);
                }
            }
            __syncthreads();
        }

        // ---- P2a: p = x @ W1^T (k-split 2-way) -> softmax partials -> ARRIVE
        {
            float acc[8] = {};
            stream16(WtH + (size_t)(3 + i) * 32768, g0, c, xlh, acc);
            if (rq == 1) {
                #pragma unroll
                for (int r = 0; r < 8; ++r) comb[r * 256 + c] = acc[r];
            }
            __syncthreads();
            if (rq == 0) {
                float p8[8];
                #pragma unroll
                for (int r = 0; r < 8; ++r) p8[r] = acc[r] + comb[r * 256 + c];
                float m8 = p8[0];
                #pragma unroll
                for (int r = 1; r < 8; ++r) m8 = fmaxf(m8, p8[r]);
                float d8 = 0.f, n8 = 0.f;
                #pragma unroll
                for (int r = 0; r < 8; ++r) {
                    const float e = __expf(p8[r] - m8);
                    d8 += e;
                    n8 += e * x32[r];
                }
                float* pb = part + (size_t)((i & 1) * 256 + bid) * 768;
                AG_ST(pb + c, m8);
                AG_ST(pb + 256 + c, d8);
                AG_ST(pb + 512 + c, n8);
            }
            bar_arrive(i + 2, flags, bid);
        }

        // ---- P2b: xU1 = x @ U1^T (k-split 2-way) — hides barrier propagation
        {
            float acc[8] = {};
            stream16(WtH + (size_t)(6 + i) * 32768, g0, c, xlh, acc);
            if (rq == 0) {
                #pragma unroll
                for (int r = 0; r < 8; ++r) comb[r * 256 + c] = acc[r];
            }
            __syncthreads();
            if (rq == 1) {
                #pragma unroll
                for (int r = 0; r < 8; ++r) xu[r] = acc[r] + comb[r * 256 + c];
            }
        }

        // ---- prefetch U2 weights (independent of barrier), then WAIT
        const unsigned* U2q = WtH + (size_t)(9 + i) * 32768;
        uint4 bu[8];
        #pragma unroll
        for (int j = 0; j < 8; ++j)
            bu[j] = *(const uint4*)(U2q + (size_t)(g0 + j) * 1024 + c * 4);
        bar_wait(i + 2, flags, false);

        // ---- phaseB: combine partials (hoisted loads + tree), sigmoid, U2
        float accU;
        {
            const float* pbase = part + (size_t)((i & 1) * 256 + b * 16 + rq * 8) * 768;
            float m[8], d[8], nn[8];
            #pragma unroll
            for (int j = 0; j < 8; ++j) {             // 24 loads all in flight
                const float* pp = pbase + (size_t)j * 768;
                m[j]  = AG_LD(pp + c);
                d[j]  = AG_LD(pp + 256 + c);
                nn[j] = AG_LD(pp + 512 + c);
            }
            #pragma unroll
            for (int st = 1; st < 8; st <<= 1) {      // tree combine 8 -> 1
                #pragma unroll
                for (int j = 0; j < 8; j += 2 * st) {
                    const float Mn = fmaxf(m[j], m[j + st]);
                    const float sa = __expf(m[j] - Mn), sb = __expf(m[j + st] - Mn);
                    d[j]  = d[j] * sa + d[j + st] * sb;
                    nn[j] = nn[j] * sa + nn[j + st] * sb;
                    m[j]  = Mn;
                }
            }
            S[rq * 256 + c] = m[0];
            S[512 + rq * 256 + c] = d[0];
            S[1024 + rq * 256 + c] = nn[0];
            __syncthreads();
            if (rq == 0) {
                const float m0 = S[c], m1 = S[256 + c];
                const float Mx = fmaxf(m0, m1);
                const float s0 = __expf(m0 - Mx), s1 = __expf(m1 - Mx);
                const float dd = S[512 + c] * s0 + S[768 + c] * s1;
                const float nv = S[1024 + c] * s0 + S[1280 + c] * s1;
                aggl32[c] = 1.f / (1.f + __expf(-(nv / dd)));
            }
            __syncthreads();
            if (tid < 128) aggh[tid] = pkh(aggl32[2 * tid], aggl32[2 * tid + 1]);
            __syncthreads();
            float au = 0.f;
            #pragma unroll
            for (int ph = 0; ph < 2; ++ph) {
                #pragma unroll
                for (int j = 0; j < 8; ++j) {
                    const uint4 w = bu[j];
                    if (ph < 1)
                        bu[j] = *(const uint4*)(U2q + (size_t)(g0 + 8 + j) * 1024 + c * 4);
                    const uint4 a = *(const uint4*)&aggh[(g0 + ph * 8 + j) * 4];
                    au = fdot2(w.x, a.x, au);
                    au = fdot2(w.y, a.y, au);
                    au = fdot2(w.z, a.z, au);
                    au = fdot2(w.w, a.w, au);
                }
            }
            S[rq * 256 + c] = au;
            __syncthreads();
            accU = S[c] + S[256 + c] + updB[i * 256 + c];
        }

        // ---- epilogue: hid update (i<2) or output write (i==2)
        if (i < 2) {
            if (rq == 1) {
                #pragma unroll
                for (int r = 0; r < 8; ++r) {
                    const float hv = (xu[r] + accU) * msk[r];
                    const float ho = __shfl_xor(hv, 1);
                    if (!(c & 1)) hidh[r * 128 + (c >> 1)] = pkh(hv, ho);
                }
            }
            __syncthreads();
        } else {
            if (rq == 1) {
                #pragma unroll
                for (int r = 0; r < 8; ++r)
                    out[(size_t)(row0 + r) * 256 + c] = xu[r] + accU;
            }
        }
    }
}

extern "C" void kernel_launch(void* const* d_in, const int* in_sizes, int n_in,
                              void* d_out, int out_size, void* d_ws, size_t ws_size,
                              hipStream_t stream) {
    const float* feat  = (const float*)d_in[0];
    const float* mask  = (const float*)d_in[1];
    const float* aggW  = (const float*)d_in[2];
    const float* aggB  = (const float*)d_in[3];
    const float* attnW = (const float*)d_in[4];
    // d_in[5] = attnB: cancels in softmax (constant along the s axis)
    const float* updW  = (const float*)d_in[6];
    const float* updB  = (const float*)d_in[7];

    unsigned* WtH = (unsigned*)d_ws;                   // 12 * 32768 uints
    float* part = (float*)(WtH + 12 * 32768);          // 2 * 256 * 768 floats
    unsigned* flags = (unsigned*)(part + 2 * 256 * 768);
    unsigned* rel   = flags + NBLK * FPAD;             // kept for layout compat

    fused_k<<<NBLK, NT, 0, stream>>>(
        feat, mask, aggW, aggB, attnW, updW, updB,
        WtH, part, flags, rel, (float*)d_out);
}

// Round 5
// 135.577 us; speedup vs baseline: 1.2482x; 1.1901x over previous
//
#include <hip/hip_runtime.h>
#include <hip/hip_fp16.h>

#define NBLK 256
#define NT   512
#define FPAD 16   // 64 B per flag slot

typedef _Float16 h2_t  __attribute__((ext_vector_type(2)));
typedef _Float16 half8 __attribute__((ext_vector_type(8)));
typedef float    f32x4 __attribute__((ext_vector_type(4)));

#define AG_LD(p)    __hip_atomic_load((p), __ATOMIC_RELAXED, __HIP_MEMORY_SCOPE_AGENT)
#define AG_ST(p, v) __hip_atomic_store((p), (v), __ATOMIC_RELAXED, __HIP_MEMORY_SCOPE_AGENT)

// pack two fp32 -> fp16 pair (RNE)
__device__ __forceinline__ unsigned pkh(float a, float b) {
    const __half2 h = __floats2half2_rn(a, b);
    return __builtin_bit_cast(unsigned, h);
}
// fp16-pair dot product with fp32 accumulate (v_dot2_f32_f16) — U2 matvec only
__device__ __forceinline__ float fdot2(unsigned w, unsigned a, float c) {
#if __has_builtin(__builtin_amdgcn_fdot2)
    return __builtin_amdgcn_fdot2(__builtin_bit_cast(h2_t, w),
                                  __builtin_bit_cast(h2_t, a), c, false);
#else
    const float2 fw = __half22float2(__builtin_bit_cast(__half2, w));
    const float2 fa = __half22float2(__builtin_bit_cast(__half2, a));
    return c + fw.x * fa.x + fw.y * fa.y;
#endif
}

__device__ __forceinline__ half8 ldw(const unsigned* p) {
    return __builtin_bit_cast(half8, *(const uint4*)p);
}
__device__ __forceinline__ f32x4 MF(half8 a, half8 b, f32x4 c) {
    return __builtin_amdgcn_mfma_f32_16x16x32_f16(a, b, c, 0, 0, 0);
}

// ---- R0's validated block0-fanout barrier, split into arrive / wait ----
__device__ __forceinline__ void bar_arrive(int n, unsigned* flags, int bid) {
    __syncthreads();
    if (threadIdx.x == 0)
        __hip_atomic_store(&flags[bid * FPAD], (unsigned)n, __ATOMIC_RELEASE,
                           __HIP_MEMORY_SCOPE_AGENT);
}
__device__ __forceinline__ void bar_wait(int n, unsigned* flags, unsigned* rel,
                                         int bid, bool fence) {
    if (bid == 0) {
        if (threadIdx.x < NBLK) {
            while ((int)__hip_atomic_load(&flags[threadIdx.x * FPAD],
                                          __ATOMIC_RELAXED,
                                          __HIP_MEMORY_SCOPE_AGENT) < n)
                __builtin_amdgcn_s_sleep(1);
        }
        __syncthreads();
        if (threadIdx.x < 16)
            __hip_atomic_store(&rel[(n * 16 + threadIdx.x) * FPAD], (unsigned)n,
                               __ATOMIC_RELEASE, __HIP_MEMORY_SCOPE_AGENT);
    } else {
        if (threadIdx.x == 0) {
            while ((int)__hip_atomic_load(&rel[(n * 16 + (bid & 15)) * FPAD],
                                          __ATOMIC_RELAXED,
                                          __HIP_MEMORY_SCOPE_AGENT) < n)
                __builtin_amdgcn_s_sleep(1);
        }
    }
    if (fence) __builtin_amdgcn_fence(__ATOMIC_ACQUIRE, "agent");
    __syncthreads();
}

// MFMA-pack (matrices 0..8): uint idx = (t*8+kc)*256 + (g*16+lc)*4 + sl, where
// lane l = g*16+lc holds col t*16+lc, k = kc*32 + g*8 + {0..7}. Identical k-map
// to the A-staging read -> any HW-internal k relabeling cancels. B-loads are
// perfectly coalesced 1 KB per wave-inst.
// Old pack (matrices 9..11, U2 fdot2 path): idx = (k>>3)*1024 + c*4 + ((k>>1)&3).

// Per-batch softmax combine (hoisted tree) + sigmoid + U2 matvec + updB.
__device__ __forceinline__ float phaseB(int i, int b, int c, int rq, int tid,
                                        const float* __restrict__ part,
                                        const unsigned* __restrict__ WtH,
                                        const float* __restrict__ updB,
                                        float* S, float* aggl32, unsigned* aggh) {
    const float* pbase = part + (size_t)((i & 1) * 256 + b * 16 + rq * 8) * 768;
    float m[8], d[8], nn[8];
    #pragma unroll
    for (int j = 0; j < 8; ++j) {                 // 24 loads all in flight
        const float* pp = pbase + (size_t)j * 768;
        m[j]  = AG_LD(pp + c);
        d[j]  = AG_LD(pp + 256 + c);
        nn[j] = AG_LD(pp + 512 + c);
    }
    #pragma unroll
    for (int st = 1; st < 8; st <<= 1) {          // tree combine 8 -> 1
        #pragma unroll
        for (int j = 0; j < 8; j += 2 * st) {
            const float Mn = fmaxf(m[j], m[j + st]);
            const float sa = __expf(m[j] - Mn), sb = __expf(m[j + st] - Mn);
            d[j]  = d[j] * sa + d[j + st] * sb;
            nn[j] = nn[j] * sa + nn[j + st] * sb;
            m[j]  = Mn;
        }
    }
    S[rq * 256 + c] = m[0];
    S[512 + rq * 256 + c] = d[0];
    S[1024 + rq * 256 + c] = nn[0];
    __syncthreads();
    if (rq == 0) {
        const float m0 = S[c], m1 = S[256 + c];
        const float Mx = fmaxf(m0, m1);
        const float s0 = __expf(m0 - Mx), s1 = __expf(m1 - Mx);
        const float dd = S[512 + c] * s0 + S[768 + c] * s1;
        const float nv = S[1024 + c] * s0 + S[1280 + c] * s1;
        aggl32[c] = 1.f / (1.f + __expf(-(nv / dd)));
    }
    __syncthreads();
    if (tid < 128) aggh[tid] = pkh(aggl32[2 * tid], aggl32[2 * tid + 1]);
    __syncthreads();
    // U2 matvec: OLD fp16 layout, k-split across rq halves
    const unsigned* Uq = WtH + (size_t)(9 + i) * 32768;
    const int g0 = rq * 16;
    uint4 buf[8];
    #pragma unroll
    for (int j = 0; j < 8; ++j)
        buf[j] = *(const uint4*)(Uq + (size_t)(g0 + j) * 1024 + c * 4);
    float au = 0.f;
    #pragma unroll
    for (int ph = 0; ph < 2; ++ph) {
        #pragma unroll
        for (int j = 0; j < 8; ++j) {
            const uint4 w = buf[j];
            if (ph < 1)
                buf[j] = *(const uint4*)(Uq + (size_t)(g0 + 8 + j) * 1024 + c * 4);
            const uint4 a = *(const uint4*)&aggh[(g0 + ph * 8 + j) * 4];
            au = fdot2(w.x, a.x, au);
            au = fdot2(w.y, a.y, au);
            au = fdot2(w.z, a.z, au);
            au = fdot2(w.w, a.w, au);
        }
    }
    __syncthreads();
    S[rq * 256 + c] = au;
    __syncthreads();
    return S[c] + S[256 + c] + updB[i * 256 + c];
}

__global__ __launch_bounds__(NT, 2) void fused_k(
    const float* __restrict__ feat,   // [16][128][256]
    const float* __restrict__ mask,   // [16][128]
    const float* __restrict__ aggW,   // [3][256][256]
    const float* __restrict__ aggB,   // [3][256]
    const float* __restrict__ attnW,  // [3][256][512]
    const float* __restrict__ updW,   // [3][256][512]
    const float* __restrict__ updB,   // [3][256]
    unsigned* __restrict__ WtH,       // 12 * 32768 uints (fp16-pair packed)
    float* __restrict__ part,         // 2 * 256 * 768
    unsigned* flags, unsigned* rel,
    float* __restrict__ out)
{
    // A-operand staging: [16 rows][132 uints] (128 k-pair uints + 16B pad),
    // rows 8-15 = zero pad. uint(r, k-pair p2) = r*132 + p2, p2 in [0,128).
    // A-frag read: lane l, chunk kc: ds_read_b128 at r=(l&15), + kc*16+(l>>4)*4
    // -> k = kc*32 + (l>>4)*8 + {0..7}.  132 mod 32 = 4 -> 2-way banks (free).
    __shared__ __align__(16) float ldsf[6408];
    unsigned* hid_uu = (unsigned*)ldsf;            // [0,2112)
    unsigned* x_uu   = (unsigned*)ldsf + 2112;     // [2112,4224)
    float*    accl   = ldsf + 4224;                // [4224,4480)
    float*    S      = ldsf + 4480;                // [4480,6016)
    float*    aggl32 = ldsf + 6016;                // [6016,6272)
    unsigned* aggh   = (unsigned*)ldsf + 6272;     // [6272,6400)
    float*    msk    = ldsf + 6400;                // [6400,6408) (outside Tl overlay)

    const int bid = blockIdx.x;
    const int tid = threadIdx.x;
    const int c   = tid & 255;
    const int rq  = tid >> 8;                 // 0..1 (phaseB k-split)
    const int wid = tid >> 6, lane = tid & 63;
    const int lr  = lane & 15, lg = lane >> 4;
    const int b   = bid >> 4, jj = bid & 15;
    const int row0 = b * 128 + jj * 8;

    // ---- P0a: stage hid0 = fp16(feat*mask) into A-layout; zero pad rows
    #pragma unroll
    for (int it = 0; it < 2; ++it) {
        const int j = it * 512 + tid, r = j >> 7, pr = j & 127;
        const float2 f = *(const float2*)(feat + (size_t)(row0 + r) * 256 + pr * 2);
        const float mv = mask[row0 + r];
        hid_uu[r * 132 + pr] = pkh(f.x * mv, f.y * mv);
    }
    for (int z = tid; z < 1056; z += NT) hid_uu[1056 + z] = 0u;
    if (tid < 8) msk[tid] = mask[row0 + tid];

    // ---- P0b: transpose + fp16-pack 12 weight mats (blocks 0..191)
    if (bid < 192) {
        float (*Tl)[65] = (float (*)[65])(ldsf + 2112);   // overlay, dead regions
        const int m = bid >> 4, t = bid & 15, tr = t >> 2, tc = t & 3;
        const float* src; int stride, off;
        if (m < 3)      { src = aggW  + (size_t)m * 65536;        stride = 256; off = 0;   }
        else if (m < 6) { src = attnW + (size_t)(m - 3) * 131072; stride = 512; off = 0;   }
        else if (m < 9) { src = updW  + (size_t)(m - 6) * 131072; stride = 512; off = 0;   }
        else            { src = updW  + (size_t)(m - 9) * 131072; stride = 512; off = 256; }
        unsigned* dstu = WtH + (size_t)m * 32768;
        #pragma unroll
        for (int it = 0; it < 2; ++it) {
            const int j = it * 512 + tid, row = j >> 4, q = (j & 15) * 4;
            const float4 v = *(const float4*)(src + (size_t)(tr * 64 + row) * stride + off + tc * 64 + q);
            Tl[row][q + 0] = v.x; Tl[row][q + 1] = v.y;
            Tl[row][q + 2] = v.z; Tl[row][q + 3] = v.w;
        }
        __syncthreads();
        #pragma unroll
        for (int it = 0; it < 4; ++it) {
            const int j = it * 512 + tid, cl = j >> 5, pr = j & 31;
            const unsigned val = pkh(Tl[cl][pr * 2], Tl[cl][pr * 2 + 1]);
            const int C = tr * 64 + cl, P = tc * 32 + pr;
            size_t idx;
            if (m < 9) {   // MFMA B-fragment pack
                const int tt = C >> 4, lc = C & 15;
                const int kc = P >> 4, g = (P >> 2) & 3, sl = P & 3;
                idx = (size_t)((tt * 8 + kc) * 256 + (g * 16 + lc) * 4 + sl);
            } else {       // old pack (U2 fdot2 path)
                idx = (size_t)(P >> 2) * 1024 + (size_t)C * 4 + (P & 3);
            }
            dstu[idx] = val;
        }
    }
    bar_arrive(1, flags, bid);
    bar_wait(1, flags, rel, bid, true);   // only fenced barrier

    for (int z = tid; z < 1056; z += NT) x_uu[1056 + z] = 0u;   // pad rows (once)

    f32x4 xu0 = {}, xu1 = {};   // U1 results (D-layout), persist across barrier

    for (int i = 0; i < 3; ++i) {
        if (i > 0) {
            const float accU = phaseB(i - 1, b, c, rq, tid, part, WtH, updB,
                                      S, aggl32, aggh);
            if (rq == 0) accl[c] = accU;
            __syncthreads();
            // hid' = (xU1 + accU) * mask, staged from D-layout into A-layout
            #pragma unroll
            for (int tt = 0; tt < 2; ++tt) {
                const int t = wid * 2 + tt;
                const f32x4 xa = tt ? xu1 : xu0;
                const float av = accl[t * 16 + lr];
                float hv[4], pv[4];
                #pragma unroll
                for (int q = 0; q < 4; ++q)
                    hv[q] = (xa[q] + av) * msk[(lg & 1) * 4 + q];
                #pragma unroll
                for (int q = 0; q < 4; ++q) pv[q] = __shfl_xor(hv[q], 1);
                if (lg < 2 && !(lr & 1)) {
                    const int p2 = t * 8 + (lr >> 1);
                    #pragma unroll
                    for (int q = 0; q < 4; ++q)
                        hid_uu[(lg * 4 + q) * 132 + p2] = pkh(hv[q], pv[q]);
                }
            }
            __syncthreads();
        }

        f32x4 xr0, xr1;   // x (D-layout, biased) for n8

        // ---- P1: x = hid @ aggW^T + aggB via MFMA (B streamed L2->VGPR)
        {
            const unsigned* W0 = WtH + (size_t)i * 32768;
            half8 a[8];
            #pragma unroll
            for (int kc = 0; kc < 8; ++kc)
                a[kc] = ldw(hid_uu + lr * 132 + kc * 16 + lg * 4);
            #pragma unroll
            for (int tt = 0; tt < 2; ++tt) {
                const int t = wid * 2 + tt;
                f32x4 acc = {};
                #pragma unroll
                for (int kc = 0; kc < 8; ++kc)
                    acc = MF(a[kc], ldw(W0 + (size_t)(t * 8 + kc) * 256 + lane * 4), acc);
                const float bb = aggB[i * 256 + t * 16 + lr];
                #pragma unroll
                for (int q = 0; q < 4; ++q) acc[q] += bb;
                if (tt) xr1 = acc; else xr0 = acc;
                float pv[4];
                #pragma unroll
                for (int q = 0; q < 4; ++q) pv[q] = __shfl_xor(acc[q], 1);
                if (lg < 2 && !(lr & 1)) {
                    const int p2 = t * 8 + (lr >> 1);
                    #pragma unroll
                    for (int q = 0; q < 4; ++q)
                        x_uu[(lg * 4 + q) * 132 + p2] = pkh(acc[q], pv[q]);
                }
            }
            __syncthreads();
        }

        // ---- P2: W1 -> softmax partials -> arrive; U1 (hides barrier); wait
        {
            const unsigned* W1 = WtH + (size_t)(3 + i) * 32768;
            const unsigned* U1 = WtH + (size_t)(6 + i) * 32768;
            half8 a2[8];
            #pragma unroll
            for (int kc = 0; kc < 8; ++kc)
                a2[kc] = ldw(x_uu + lr * 132 + kc * 16 + lg * 4);
            float* pb = part + (size_t)((i & 1) * 256 + bid) * 768;
            #pragma unroll
            for (int tt = 0; tt < 2; ++tt) {
                const int t = wid * 2 + tt;
                f32x4 acc = {};
                #pragma unroll
                for (int kc = 0; kc < 8; ++kc)
                    acc = MF(a2[kc], ldw(W1 + (size_t)(t * 8 + kc) * 256 + lane * 4), acc);
                // per-col partials: rows 0-3 in lg==0 lanes, rows 4-7 in lg==1
                const f32x4 xa = tt ? xr1 : xr0;
                float m4 = fmaxf(fmaxf(acc[0], acc[1]), fmaxf(acc[2], acc[3]));
                const float m8 = fmaxf(m4, __shfl_xor(m4, 16));
                float d4 = 0.f, n4 = 0.f;
                #pragma unroll
                for (int q = 0; q < 4; ++q) {
                    const float e = __expf(acc[q] - m8);
                    d4 += e;
                    n4 += e * xa[q];
                }
                const float d8 = d4 + __shfl_xor(d4, 16);
                const float n8 = n4 + __shfl_xor(n4, 16);
                if (lg == 0) {
                    const int cc = t * 16 + lr;
                    AG_ST(pb + cc, m8);
                    AG_ST(pb + 256 + cc, d8);
                    AG_ST(pb + 512 + cc, n8);
                }
            }
            bar_arrive(i + 2, flags, bid);
            #pragma unroll
            for (int tt = 0; tt < 2; ++tt) {
                const int t = wid * 2 + tt;
                f32x4 acc = {};
                #pragma unroll
                for (int kc = 0; kc < 8; ++kc)
                    acc = MF(a2[kc], ldw(U1 + (size_t)(t * 8 + kc) * 256 + lane * 4), acc);
                if (tt) xu1 = acc; else xu0 = acc;
            }
            bar_wait(i + 2, flags, rel, bid, false);   // no fence: L2 stays warm
        }
    }

    // ---- final combine + epilogue: out = xU1 + accU
    {
        const float accU = phaseB(2, b, c, rq, tid, part, WtH, updB, S, aggl32, aggh);
        if (rq == 0) accl[c] = accU;
        __syncthreads();
        #pragma unroll
        for (int tt = 0; tt < 2; ++tt) {
            const int t = wid * 2 + tt;
            const f32x4 xa = tt ? xu1 : xu0;
            const float av = accl[t * 16 + lr];
            if (lg < 2) {
                #pragma unroll
                for (int q = 0; q < 4; ++q)
                    out[(size_t)(row0 + lg * 4 + q) * 256 + t * 16 + lr] = xa[q] + av;
            }
        }
    }
}

extern "C" void kernel_launch(void* const* d_in, const int* in_sizes, int n_in,
                              void* d_out, int out_size, void* d_ws, size_t ws_size,
                              hipStream_t stream) {
    const float* feat  = (const float*)d_in[0];
    const float* mask  = (const float*)d_in[1];
    const float* aggW  = (const float*)d_in[2];
    const float* aggB  = (const float*)d_in[3];
    const float* attnW = (const float*)d_in[4];
    // d_in[5] = attnB: cancels in softmax (constant along the s axis)
    const float* updW  = (const float*)d_in[6];
    const float* updB  = (const float*)d_in[7];

    unsigned* WtH = (unsigned*)d_ws;                   // 12 * 32768 uints
    float* part = (float*)(WtH + 12 * 32768);          // 2 * 256 * 768 floats
    unsigned* flags = (unsigned*)(part + 2 * 256 * 768);
    unsigned* rel   = flags + NBLK * FPAD;             // barriers * 16 lines

    fused_k<<<NBLK, NT, 0, stream>>>(
        feat, mask, aggW, aggB, attnW, updW, updB,
        WtH, part, flags, rel, (float*)d_out);
}